// Round 5
// baseline (18779.668 us; speedup 1.0000x reference)
//
#include <hip/hip_runtime.h>

#define HS    128
#define INP   23
#define NF    24      // features incl. time
#define NGATE 512     // 4*HS
#define TLEN  1024
#define BATCH 512

__device__ __forceinline__ float fexp(float x) {
    return __builtin_amdgcn_exp2f(x * 1.4426950408889634f);
}
__device__ __forceinline__ float fsigmoid(float x) {
    return __builtin_amdgcn_rcpf(1.0f + fexp(-x));
}
__device__ __forceinline__ float ftanh(float x) {
    // tanh(x) = 2*sigmoid(2x) - 1 ; saturates correctly for |x| large
    return 2.0f * fsigmoid(2.0f * x) - 1.0f;
}

// 2 batch rows per block; 128+24 weight columns pinned in VGPRs.
//
// Register-budget history (the whole game so far):
//   r1: no pin            -> compiler remats U from L2 every step (2.85 ms)
//   r3: pin + lb(512,2)   -> VGPR capped 128, pinned values SPILL (19 ms)
//   r4: pin + lb(512,1)   -> VGPR still 128: launch_bounds' 2nd arg never
//                            reaches the backend; default heuristic = 4
//                            waves/EU = 128-VGPR budget.
// Fix: native clang attributes. waves_per_eu(2,2) => backend VGPR budget
// 512/2 = 256; flat_work_group_size(512,512) pins exact block shape.
__global__
__attribute__((amdgpu_flat_work_group_size(512, 512)))
__attribute__((amdgpu_waves_per_eu(2, 2)))
void lstm_fused2(const float* __restrict__ points,
                 const float* __restrict__ times,
                 const float* __restrict__ W,
                 const float* __restrict__ U,
                 const float* __restrict__ bias,
                 const float* __restrict__ Wc,
                 const float* __restrict__ bc,
                 float* __restrict__ out)
{
    const int b0 = blockIdx.x * 2;      // rows b0, b0+1
    const int g  = threadIdx.x;         // gate column 0..511

    __shared__ __align__(16) float h_lds[2][HS];
    __shared__ __align__(16) float gates[2][NGATE];
    __shared__ __align__(16) float xbuf[2][2][32];   // [dbuf][row][feat], 24 used
    __shared__ float opart[2][2][2];                 // [row][half][col]

    // ---- preload weights into registers (coalesced across threads) ----
    float Ucol[HS];
    #pragma unroll
    for (int k = 0; k < HS; ++k) Ucol[k] = U[k * NGATE + g];
    float Wcol[NF];
    #pragma unroll
    for (int f = 0; f < NF; ++f) Wcol[f] = W[f * NGATE + g];

    // PIN: volatile asm cannot be rematerialized -> compiler must keep these
    // in VGPRs instead of re-loading from L2 every timestep. Requires the
    // 256-VGPR budget from waves_per_eu(2,2) above, else it spills.
    #pragma unroll
    for (int k = 0; k < HS; ++k) asm volatile("" : "+v"(Ucol[k]));
    #pragma unroll
    for (int f = 0; f < NF; ++f) asm volatile("" : "+v"(Wcol[f]));

    const float bcol = bias[g];
    const float bc0 = bc[0], bc1 = bc[1];

    // cell state: threads 0..127 own row0 col j; threads 128..255 own row1 col j
    float wc0 = 0.0f, wc1 = 0.0f, c = 0.0f;
    if (g < 2 * HS) {
        const int j = g & (HS - 1);
        wc0 = Wc[2 * j];
        wc1 = Wc[2 * j + 1];
        h_lds[g >> 7][j] = 0.0f;   // h0 = 0
    }

    const float* px0 = points + (size_t)(b0 + 0) * TLEN * INP;
    const float* px1 = points + (size_t)(b0 + 1) * TLEN * INP;
    const float* pt0 = times  + (size_t)(b0 + 0) * TLEN;
    const float* pt1 = times  + (size_t)(b0 + 1) * TLEN;
    float2* pout0 = (float2*)out + (size_t)(b0 + 0) * TLEN;
    float2* pout1 = (float2*)out + (size_t)(b0 + 1) * TLEN;

    // stage x for t = 0
    if (g < INP)            xbuf[0][0][g]      = px0[g];
    else if (g == INP)      xbuf[0][0][INP]    = pt0[0];
    else if (g >= 64 && g < 64 + INP) xbuf[0][1][g - 64] = px1[g - 64];
    else if (g == 64 + INP) xbuf[0][1][INP]    = pt1[0];
    __syncthreads();

    for (int t = 0; t < TLEN; ++t) {
        const int cur = t & 1, nxt = cur ^ 1;

        // prefetch x for t+1 on waves 4-7 (waves 0-3 own the cell update);
        // consumed after 2 barriers -> latency hidden.
        if (t + 1 < TLEN) {
            const int pg = g - 256;   // 0..255 on waves 4-7
            if (pg >= 0) {
                if (pg < INP)            xbuf[nxt][0][pg]      = px0[(t + 1) * INP + pg];
                else if (pg == INP)      xbuf[nxt][0][INP]    = pt0[t + 1];
                else if (pg >= 64 && pg < 64 + INP)
                                         xbuf[nxt][1][pg - 64] = px1[(t + 1) * INP + (pg - 64)];
                else if (pg == 64 + INP) xbuf[nxt][1][INP]    = pt1[t + 1];
            }
        }

        // ---- gate pre-activation for BOTH rows: bias + x.W + h.U ----
        float a00 = bcol, a01 = 0.0f, a02 = 0.0f, a03 = 0.0f;
        float a10 = bcol, a11 = 0.0f, a12 = 0.0f, a13 = 0.0f;
        const float4* h40 = (const float4*)h_lds[0];
        const float4* h41 = (const float4*)h_lds[1];
        #pragma unroll
        for (int kk = 0; kk < HS / 4; ++kk) {
            const float4 h0v = h40[kk];
            const float4 h1v = h41[kk];
            a00 = fmaf(h0v.x, Ucol[4 * kk + 0], a00);
            a01 = fmaf(h0v.y, Ucol[4 * kk + 1], a01);
            a02 = fmaf(h0v.z, Ucol[4 * kk + 2], a02);
            a03 = fmaf(h0v.w, Ucol[4 * kk + 3], a03);
            a10 = fmaf(h1v.x, Ucol[4 * kk + 0], a10);
            a11 = fmaf(h1v.y, Ucol[4 * kk + 1], a11);
            a12 = fmaf(h1v.z, Ucol[4 * kk + 2], a12);
            a13 = fmaf(h1v.w, Ucol[4 * kk + 3], a13);
        }
        const float4* x40 = (const float4*)xbuf[cur][0];
        const float4* x41 = (const float4*)xbuf[cur][1];
        #pragma unroll
        for (int ff = 0; ff < NF / 4; ++ff) {
            const float4 x0v = x40[ff];
            const float4 x1v = x41[ff];
            a00 = fmaf(x0v.x, Wcol[4 * ff + 0], a00);
            a01 = fmaf(x0v.y, Wcol[4 * ff + 1], a01);
            a02 = fmaf(x0v.z, Wcol[4 * ff + 2], a02);
            a03 = fmaf(x0v.w, Wcol[4 * ff + 3], a03);
            a10 = fmaf(x1v.x, Wcol[4 * ff + 0], a10);
            a11 = fmaf(x1v.y, Wcol[4 * ff + 1], a11);
            a12 = fmaf(x1v.z, Wcol[4 * ff + 2], a12);
            a13 = fmaf(x1v.w, Wcol[4 * ff + 3], a13);
        }
        const float pre0 = (a00 + a01) + (a02 + a03);
        const float pre1 = (a10 + a11) + (a12 + a13);

        // sigmoid for i,f,o ; tanh for g-gate (columns [256,384)) — wave-uniform
        const bool isg = (g >= 2 * HS && g < 3 * HS);
        gates[0][g] = isg ? ftanh(pre0) : fsigmoid(pre0);
        gates[1][g] = isg ? ftanh(pre1) : fsigmoid(pre1);
        __syncthreads();   // barrier A: gates published

        if (g < 2 * HS) {  // waves 0-3 exactly: row = g>>7, col = g&127
            const int row = g >> 7, j = g & (HS - 1);
            const float ig = gates[row][j];
            const float fg = gates[row][HS + j];
            const float gg = gates[row][2 * HS + j];
            const float og = gates[row][3 * HS + j];
            c = fg * c + ig * gg;
            const float h = og * ftanh(c);
            h_lds[row][j] = h;

            // output projection partials: h . Wc (2 cols), 64-lane reduce
            float p0 = h * wc0, p1 = h * wc1;
            #pragma unroll
            for (int off = 32; off; off >>= 1) {
                p0 += __shfl_down(p0, off);
                p1 += __shfl_down(p1, off);
            }
            if ((g & 63) == 0) {
                opart[row][(g >> 6) & 1][0] = p0;
                opart[row][(g >> 6) & 1][1] = p1;
            }
        }
        __syncthreads();   // barrier B: h (and opart) published

        if (g < 2 * HS && (g & 127) == 0) {   // g==0 (row0), g==128 (row1)
            const int row = g >> 7;
            const float o0 = fsigmoid(opart[row][0][0] + opart[row][1][0] + bc0);
            const float o1 = fsigmoid(opart[row][0][1] + opart[row][1][1] + bc1);
            (row ? pout1 : pout0)[t] = make_float2(o0, o1);
        }
    }
}

extern "C" void kernel_launch(void* const* d_in, const int* in_sizes, int n_in,
                              void* d_out, int out_size, void* d_ws, size_t ws_size,
                              hipStream_t stream) {
    const float* points = (const float*)d_in[0];
    const float* times  = (const float*)d_in[1];
    const float* W      = (const float*)d_in[2];
    const float* U      = (const float*)d_in[3];
    const float* bias   = (const float*)d_in[4];
    const float* Wc     = (const float*)d_in[5];
    const float* bc     = (const float*)d_in[6];
    float* out = (float*)d_out;

    lstm_fused2<<<dim3(BATCH / 2), dim3(NGATE), 0, stream>>>(
        points, times, W, U, bias, Wc, bc, out);
}

// Round 7
// 1843.850 us; speedup vs baseline: 10.1850x; 10.1850x over previous
//
#include <hip/hip_runtime.h>

#define HS    128
#define INP   23
#define NGATE 512     // 4*HS
#define TLEN  1024
#define BATCH 512

__device__ __forceinline__ float fexp(float x) {
    return __builtin_amdgcn_exp2f(x * 1.4426950408889634f);
}
__device__ __forceinline__ float fsigmoid(float x) {
    return __builtin_amdgcn_rcpf(1.0f + fexp(-x));
}
__device__ __forceinline__ float ftanh(float x) {
    return 2.0f * fsigmoid(2.0f * x) - 1.0f;
}

// K-SPLIT STRUCTURE (round 7 = round 6 + row-1 bias fix).
// History: r1 no-pin -> U remat from L2 each step (2.85ms). r3/r4/r5: 152
// pinned regs vs a VGPR budget that is ALWAYS 128 -> scratch spill (19ms).
// r6: k-split (76 pinned regs/thread, fits 128) but row-1's gate chains
// were seeded with 0 instead of bias -> absmax 3 bf16 ulps, fail by 2.7%.
// Fix: d0 = bcol (bias seeded in BOTH rows' kh=0 chains).
__global__
__attribute__((amdgpu_flat_work_group_size(1024, 1024)))
__attribute__((amdgpu_waves_per_eu(4)))
void lstm_ksplit(const float* __restrict__ points,
                 const float* __restrict__ times,
                 const float* __restrict__ W,
                 const float* __restrict__ U,
                 const float* __restrict__ bias,
                 const float* __restrict__ Wc,
                 const float* __restrict__ bc,
                 float* __restrict__ out)
{
    const int b0  = blockIdx.x * 2;      // batch rows b0, b0+1
    const int tid = threadIdx.x;
    const int g   = tid & (NGATE - 1);   // gate column
    const int kh  = tid >> 9;            // k-half: 0 -> k<64, 1 -> k>=64

    __shared__ __align__(16) float h_lds[2][2][64];    // [khalf][row][j]
    __shared__ __align__(16) float part[2][2][NGATE];  // [kh][row][g]
    __shared__ __align__(16) float xbuf[2][2][32];     // [dbuf][row][slot]
    __shared__ float opart[2][2][2];                   // [row][half][col]

    // ---- per-thread weight slice in registers (76 values, fits in 128) ----
    float Uc[64];
    #pragma unroll
    for (int k = 0; k < 64; ++k) Uc[k] = U[(kh * 64 + k) * NGATE + g];
    float Wr[12];
    #pragma unroll
    for (int f = 0; f < 12; ++f) Wr[f] = W[(kh * 12 + f) * NGATE + g];
    // pin against rematerialization (r1 failure mode)
    #pragma unroll
    for (int k = 0; k < 64; ++k) asm volatile("" : "+v"(Uc[k]));
    #pragma unroll
    for (int f = 0; f < 12; ++f) asm volatile("" : "+v"(Wr[f]));

    const float bcol = (kh == 0) ? bias[g] : 0.0f;
    const float bc0 = bc[0], bc1 = bc[1];

    // cell-update ownership: tid<256, r = tid>>7, j = tid&127
    float wc0 = 0.0f, wc1 = 0.0f, c = 0.0f;
    if (tid < 256) {
        const int j = tid & (HS - 1);
        wc0 = Wc[2 * j];
        wc1 = Wc[2 * j + 1];
        h_lds[(j >> 6)][tid >> 7][j & 63] = 0.0f;   // h0 = 0
    }

    const float* px0 = points + (size_t)(b0 + 0) * TLEN * INP;
    const float* px1 = points + (size_t)(b0 + 1) * TLEN * INP;
    const float* pt0 = times  + (size_t)(b0 + 0) * TLEN;
    const float* pt1 = times  + (size_t)(b0 + 1) * TLEN;

    // x slot layout: feature f -> slot f (f<12) or 16+(f-12); time(f=23)->27.
    // Keeps each k-half's 12 features 16B-aligned for float4 reads.
    // stage x(t=0): waves 8-15
    {
        const int pg = tid - 512;            // 0..511 on kh=1 threads
        if (pg >= 0 && pg < 128) {
            const int r = pg >> 6, f = pg & 63;
            if (f < 24) {
                const float* px = r ? px1 : px0;
                const float* pt = r ? pt1 : pt0;
                const int slot = f + ((f >= 12) ? 4 : 0);
                xbuf[0][r][slot] = (f < 23) ? px[f] : pt[0];
            }
        }
    }
    __syncthreads();

    for (int t = 0; t < TLEN; ++t) {
        const int cur = t & 1, nxt = cur ^ 1;

        // prefetch x(t+1) on waves 8-15 (latency hidden behind 2 barriers)
        if (t + 1 < TLEN) {
            const int pg = tid - 512;
            if (pg >= 0 && pg < 128) {
                const int r = pg >> 6, f = pg & 63;
                if (f < 24) {
                    const float* px = r ? px1 : px0;
                    const float* pt = r ? pt1 : pt0;
                    const int slot = f + ((f >= 12) ? 4 : 0);
                    xbuf[nxt][r][slot] = (f < 23) ? px[(t + 1) * INP + f] : pt[t + 1];
                }
            }
        }

        // ---- phase 1: partial dot products (both rows), 152 FMA/thread ----
        float a0 = bcol, a1 = 0.0f, a2 = 0.0f, a3 = 0.0f;   // row 0
        float d0 = bcol, d1 = 0.0f, d2 = 0.0f, d3 = 0.0f;   // row 1 (r6 bug: was 0)
        const float4* h40 = (const float4*)h_lds[kh][0];
        const float4* h41 = (const float4*)h_lds[kh][1];
        #pragma unroll
        for (int kk = 0; kk < 16; ++kk) {
            const float4 h0v = h40[kk];
            const float4 h1v = h41[kk];
            a0 = fmaf(h0v.x, Uc[4 * kk + 0], a0);
            a1 = fmaf(h0v.y, Uc[4 * kk + 1], a1);
            a2 = fmaf(h0v.z, Uc[4 * kk + 2], a2);
            a3 = fmaf(h0v.w, Uc[4 * kk + 3], a3);
            d0 = fmaf(h1v.x, Uc[4 * kk + 0], d0);
            d1 = fmaf(h1v.y, Uc[4 * kk + 1], d1);
            d2 = fmaf(h1v.z, Uc[4 * kk + 2], d2);
            d3 = fmaf(h1v.w, Uc[4 * kk + 3], d3);
        }
        const float4* x40 = (const float4*)(&xbuf[cur][0][kh * 16]);
        const float4* x41 = (const float4*)(&xbuf[cur][1][kh * 16]);
        #pragma unroll
        for (int ff = 0; ff < 3; ++ff) {
            const float4 x0v = x40[ff];
            const float4 x1v = x41[ff];
            a0 = fmaf(x0v.x, Wr[4 * ff + 0], a0);
            a1 = fmaf(x0v.y, Wr[4 * ff + 1], a1);
            a2 = fmaf(x0v.z, Wr[4 * ff + 2], a2);
            a3 = fmaf(x0v.w, Wr[4 * ff + 3], a3);
            d0 = fmaf(x1v.x, Wr[4 * ff + 0], d0);
            d1 = fmaf(x1v.y, Wr[4 * ff + 1], d1);
            d2 = fmaf(x1v.z, Wr[4 * ff + 2], d2);
            d3 = fmaf(x1v.w, Wr[4 * ff + 3], d3);
        }
        part[kh][0][g] = (a0 + a1) + (a2 + a3);
        part[kh][1][g] = (d0 + d1) + (d2 + d3);
        __syncthreads();   // barrier A: partials published; h(t) reads done

        // ---- phase 2: waves 0-3 combine + activations + cell update ----
        if (tid < 256) {
            const int r = tid >> 7, j = tid & (HS - 1);
            const float pi = part[0][r][j]           + part[1][r][j];
            const float pf = part[0][r][HS + j]      + part[1][r][HS + j];
            const float pg_ = part[0][r][2 * HS + j] + part[1][r][2 * HS + j];
            const float po = part[0][r][3 * HS + j]  + part[1][r][3 * HS + j];
            const float ig = fsigmoid(pi);
            const float fg = fsigmoid(pf);
            const float gg = ftanh(pg_);
            const float og = fsigmoid(po);
            c = fg * c + ig * gg;
            const float h = og * ftanh(c);
            h_lds[j >> 6][r][j & 63] = h;

            // output projection partials: h . Wc, 64-lane reduce
            float p0 = h * wc0, p1 = h * wc1;
            #pragma unroll
            for (int off = 32; off; off >>= 1) {
                p0 += __shfl_down(p0, off);
                p1 += __shfl_down(p1, off);
            }
            if ((tid & 63) == 0) {
                opart[r][j >> 6][0] = p0;
                opart[r][j >> 6][1] = p1;
            }
        }
        __syncthreads();   // barrier B: h(t+1) + opart published

        if (tid < 256 && (tid & 127) == 0) {   // tid 0 -> row0, tid 128 -> row1
            const int r = tid >> 7;
            const float o0 = fsigmoid(opart[r][0][0] + opart[r][1][0] + bc0);
            const float o1 = fsigmoid(opart[r][0][1] + opart[r][1][1] + bc1);
            ((float2*)out)[(size_t)(b0 + r) * TLEN + t] = make_float2(o0, o1);
        }
    }
}

extern "C" void kernel_launch(void* const* d_in, const int* in_sizes, int n_in,
                              void* d_out, int out_size, void* d_ws, size_t ws_size,
                              hipStream_t stream) {
    const float* points = (const float*)d_in[0];
    const float* times  = (const float*)d_in[1];
    const float* W      = (const float*)d_in[2];
    const float* U      = (const float*)d_in[3];
    const float* bias   = (const float*)d_in[4];
    const float* Wc     = (const float*)d_in[5];
    const float* bc     = (const float*)d_in[6];
    float* out = (float*)d_out;

    lstm_ksplit<<<dim3(BATCH / 2), dim3(1024), 0, stream>>>(
        points, times, W, U, bias, Wc, bc, out);
}